// Round 3
// baseline (735.094 us; speedup 1.0000x reference)
//
#include <hip/hip_runtime.h>
#include <stdint.h>

typedef unsigned short u16;
typedef __attribute__((ext_vector_type(8))) short short8;   // 8 x bf16 (4 VGPRs)
typedef __attribute__((ext_vector_type(4))) float floatx4;  // MFMA 16x16 C/D

__device__ __forceinline__ u16 f2bf(float f) {
  union { float f; unsigned u; } v; v.f = f;
  return (u16)((v.u + 0x7FFFu + ((v.u >> 16) & 1u)) >> 16);  // RNE
}
__device__ __forceinline__ void gl_lds16(const void* g, void* l) {
  __builtin_amdgcn_global_load_lds((const __attribute__((address_space(1))) void*)g,
                                   (__attribute__((address_space(3))) void*)l, 16, 0, 0);
}
__device__ __forceinline__ float exp2_fast(float x) {
#if __has_builtin(__builtin_amdgcn_exp2f)
  return __builtin_amdgcn_exp2f(x);
#else
  return exp2f(x);
#endif
}

// ---------------- prep: cast x (fp32 -> bf16), 8 elems/thread ----------------
__global__ __launch_bounds__(256) void k_cast_x(const float* __restrict__ x, u16* __restrict__ xb) {
  int t = blockIdx.x * 256 + threadIdx.x;
  const float4* xv = (const float4*)x;
  float4 a = xv[2 * t], b = xv[2 * t + 1];
  short8 o;
  o[0] = f2bf(a.x); o[1] = f2bf(a.y); o[2] = f2bf(a.z); o[3] = f2bf(a.w);
  o[4] = f2bf(b.x); o[5] = f2bf(b.y); o[6] = f2bf(b.z); o[7] = f2bf(b.w);
  ((short8*)xb)[t] = o;
}

// ------------- prep: transpose+cast w_qkv [512,1536] and w_out [512,512] -----
__global__ __launch_bounds__(256) void k_prep_w(const float* __restrict__ wqkv, const float* __restrict__ wout,
                                                u16* __restrict__ wqkvT, u16* __restrict__ woutT) {
  int t = blockIdx.x * 256 + threadIdx.x;
  if (t < 786432) {
    int n = t >> 9, k = t & 511;
    wqkvT[t] = f2bf(wqkv[k * 1536 + n]);
  } else {
    int u = t - 786432;
    int n = u >> 9, k = u & 511;
    woutT[u] = f2bf(wout[k * 512 + n]);
  }
}

// ---- prep: bias pre-swizzled to attn lane order, value = (b-8)*log2e bf16 ---
// memory layout (u16): [h][qt][kt][w][quad][l15][ti][r][tj]; one thread = 8 tj.
__global__ __launch_bounds__(256) void k_prep_bias(const int* __restrict__ rel, const float* __restrict__ tab,
                                                   u16* __restrict__ biasb) {
  int t = blockIdx.x * 256 + threadIdx.x;   // 1,048,576 threads
  int r    = t & 3;
  int ti   = (t >> 2) & 1;
  int l15  = (t >> 3) & 15;
  int quad = (t >> 7) & 3;
  int w    = (t >> 9) & 3;
  int kt   = (t >> 11) & 7;
  int qt   = (t >> 14) & 7;
  int h    = t >> 17;
  int qrow = qt * 128 + w * 32 + ti * 16 + quad * 4 + r;
  const int* rr = rel + qrow * 1024 + kt * 128 + l15;
  short8 o;
  #pragma unroll
  for (int tj = 0; tj < 8; tj++) {
    int idx = rr[tj * 16];
    o[tj] = f2bf((tab[idx * 8 + h] - 8.0f) * 1.44269504f);
  }
  ((short8*)biasb)[t] = o;
}

// ---------------- GEMM1: qkv = xb @ wqkvT^T -> Q,K [b,h,n,d], V^T [b,h,d,n] --
__global__ __launch_bounds__(256) void k_gemm_qkv(const u16* __restrict__ xb, const u16* __restrict__ wT,
                                                  u16* __restrict__ qbuf, u16* __restrict__ kbuf,
                                                  u16* __restrict__ vtbuf) {
  __shared__ u16 sm[17408];
  const int bn = blockIdx.x, bm = blockIdx.y;
  const int tid = threadIdx.x, w = tid >> 6, lane = tid & 63;
  const int quad = lane >> 4, l15 = lane & 15;
  const int wr = w >> 1, wc = w & 1;
  const u16* Ag = xb + (size_t)bm * 128 * 512;
  const u16* Bg = wT + (size_t)bn * 128 * 512;
  floatx4 acc[4][4];
  floatx4 zero = {0.f, 0.f, 0.f, 0.f};
  #pragma unroll
  for (int i = 0; i < 4; i++)
    #pragma unroll
    for (int j = 0; j < 4; j++) acc[i][j] = zero;

  for (int kb = 0; kb < 512; kb += 32) {
    __syncthreads();
    #pragma unroll
    for (int i = 0; i < 2; i++) {
      int c = w * 128 + i * 64 + lane;
      int row = c >> 2, col = (c & 3) * 8;
      gl_lds16(Ag + (size_t)row * 512 + kb + col, &sm[(w * 128 + i * 64) * 8]);
      gl_lds16(Bg + (size_t)row * 512 + kb + col, &sm[4096 + (w * 128 + i * 64) * 8]);
    }
    __syncthreads();
    short8 af[4], bf[4];
    #pragma unroll
    for (int ti = 0; ti < 4; ti++)
      af[ti] = *(const short8*)&sm[(wr * 64 + ti * 16 + l15) * 32 + quad * 8];
    #pragma unroll
    for (int tj = 0; tj < 4; tj++)
      bf[tj] = *(const short8*)&sm[4096 + (wc * 64 + tj * 16 + l15) * 32 + quad * 8];
    #pragma unroll
    for (int ti = 0; ti < 4; ti++)
      #pragma unroll
      for (int tj = 0; tj < 4; tj++)
        acc[ti][tj] = __builtin_amdgcn_mfma_f32_16x16x32_bf16(af[ti], bf[tj], acc[ti][tj], 0, 0, 0);
  }
  __syncthreads();
  #pragma unroll
  for (int ti = 0; ti < 4; ti++)
    #pragma unroll
    for (int tj = 0; tj < 4; tj++)
      #pragma unroll
      for (int r = 0; r < 4; r++)
        sm[(wr * 64 + ti * 16 + quad * 4 + r) * 136 + wc * 64 + tj * 16 + l15] = f2bf(acc[ti][tj][r]);
  __syncthreads();
  const int b = bm >> 3;
  const int nrow0 = (bm & 7) * 128;
  if (bn < 8) {
    u16* dst = (bn < 4) ? qbuf : kbuf;
    #pragma unroll
    for (int i = 0; i < 8; i++) {
      int chunk = i * 256 + tid;
      int r = chunk >> 4, c8 = chunk & 15;
      int nin = (bn & 3) * 128 + c8 * 8;
      int h = nin >> 6, d = nin & 63;
      uint4 val = *(const uint4*)&sm[r * 136 + c8 * 8];
      *(uint4*)&dst[(((size_t)(b * 8 + h)) * 1024 + nrow0 + r) * 64 + d] = val;
    }
  } else {
    #pragma unroll
    for (int i = 0; i < 8; i++) {
      int chunk = i * 256 + tid;
      int dcol = chunk & 127, nr8 = chunk >> 7;
      int nin = (bn & 3) * 128 + dcol;
      int h = nin >> 6, d = nin & 63;
      short8 v;
      #pragma unroll
      for (int j = 0; j < 8; j++) v[j] = (short)sm[(nr8 * 8 + j) * 136 + dcol];
      *(short8*)&vtbuf[(((size_t)(b * 8 + h)) * 64 + d) * 1024 + nrow0 + nr8 * 8] = v;
    }
  }
}

// ---------------- flash attention v3: barrier-free, P-only LDS ---------------
// K/V/Q/bias fragments are loaded directly from global (16B MFMA-B-layout
// vectors; K is [n,d], V pre-transposed [d,n]). P (the only cross-format
// transform) is wave-private: each wave writes and reads ONLY its own 32 q
// rows, so NO __syncthreads anywhere in the main loop. LDS = 4 x 8KB P.
__global__ __launch_bounds__(256, 3) void k_attn(const u16* __restrict__ qbuf, const u16* __restrict__ kbuf,
                                                 const u16* __restrict__ vtbuf, const u16* __restrict__ biasb,
                                                 u16* __restrict__ attn_out) {
  __shared__ u16 sm[16384];                     // P only: [wave][32][128] swizzled
  const int b = blockIdx.x, h = blockIdx.y >> 3, qt = blockIdx.y & 7;
  const int tid = threadIdx.x, w = tid >> 6, lane = tid & 63;
  const int quad = lane >> 4, l15 = lane & 15;
  const int xm = l15 & 7;
  u16* pw = &sm[w * 4096];
  const size_t bh = (size_t)(b * 8 + h);
  const u16* qg = qbuf + (bh * 1024 + (size_t)qt * 128) * 64;
  const u16* kg = kbuf + bh * 1024 * 64;
  const u16* vg = vtbuf + bh * 64 * 1024;
  const u16* bg = biasb + (size_t)h * 1048576 + (size_t)qt * 131072 +
                  (size_t)w * 4096 + quad * 1024 + l15 * 64;

  // Q fragments: direct 16B global loads (A-layout: lane row = l15)
  short8 qf[2][2];
  #pragma unroll
  for (int ti = 0; ti < 2; ti++)
    #pragma unroll
    for (int kk = 0; kk < 2; kk++)
      qf[ti][kk] = *(const short8*)&qg[(w * 32 + ti * 16 + l15) * 64 + kk * 32 + quad * 8];

  floatx4 oacc[2][4];
  floatx4 zero = {0.f, 0.f, 0.f, 0.f};
  #pragma unroll
  for (int i = 0; i < 2; i++)
    #pragma unroll
    for (int j = 0; j < 4; j++) oacc[i][j] = zero;
  float lrow[2][4];
  #pragma unroll
  for (int i = 0; i < 2; i++)
    #pragma unroll
    for (int r = 0; r < 4; r++) lrow[i][r] = 0.f;

  const float SC = 0.125f * 1.44269504f;

  for (int kt = 0; kt < 8; kt++) {
    const u16* kgt = kg + (size_t)kt * 128 * 64;
    const u16* vgt = vg + kt * 128;
    const u16* bkt = bg + kt * 16384;

    #pragma unroll
    for (int tjh = 0; tjh < 2; tjh++) {
      // bias for this half (pre-swizzled, pre-folded (b-8)*log2e)
      uint2 bu[2][4];
      #pragma unroll
      for (int ti = 0; ti < 2; ti++)
        #pragma unroll
        for (int r = 0; r < 4; r++)
          bu[ti][r] = *(const uint2*)&bkt[(ti * 4 + r) * 8 + tjh * 4];
      // K fragments for 64 kv cols: direct global 16B loads (B-layout)
      short8 kfh[4][2];
      #pragma unroll
      for (int tjl = 0; tjl < 4; tjl++)
        #pragma unroll
        for (int kk = 0; kk < 2; kk++)
          kfh[tjl][kk] = *(const short8*)&kgt[((tjh * 4 + tjl) * 16 + l15) * 64 + kk * 32 + quad * 8];
      // S = Q K^T
      floatx4 sacc[2][4];
      #pragma unroll
      for (int tjl = 0; tjl < 4; tjl++) { sacc[0][tjl] = zero; sacc[1][tjl] = zero; }
      #pragma unroll
      for (int tjl = 0; tjl < 4; tjl++)
        #pragma unroll
        for (int kk = 0; kk < 2; kk++) {
          sacc[0][tjl] = __builtin_amdgcn_mfma_f32_16x16x32_bf16(qf[0][kk], kfh[tjl][kk], sacc[0][tjl], 0, 0, 0);
          sacc[1][tjl] = __builtin_amdgcn_mfma_f32_16x16x32_bf16(qf[1][kk], kfh[tjl][kk], sacc[1][tjl], 0, 0, 0);
        }
      // softmax (no max-subtract) + P -> wave-private LDS (swizzled)
      #pragma unroll
      for (int ti = 0; ti < 2; ti++)
        #pragma unroll
        for (int r = 0; r < 4; r++) {
          int lr = ti * 16 + quad * 4 + r;      // row within wave's 32
          int wm = lr & 7;
          unsigned blo = bu[ti][r].x, bhi = bu[ti][r].y;
          float bf32[4];
          bf32[0] = __builtin_bit_cast(float, blo << 16);
          bf32[1] = __builtin_bit_cast(float, blo & 0xFFFF0000u);
          bf32[2] = __builtin_bit_cast(float, bhi << 16);
          bf32[3] = __builtin_bit_cast(float, bhi & 0xFFFF0000u);
          float rs = 0.f;
          #pragma unroll
          for (int tjl = 0; tjl < 4; tjl++) {
            int tj = tjh * 4 + tjl;
            float p = exp2_fast(sacc[ti][tjl][r] * SC + bf32[tjl]);
            rs += p;
            unsigned pu = __builtin_bit_cast(unsigned, p);
            int cc = (2 * tj + (l15 >> 3)) ^ wm;
            pw[lr * 128 + cc * 8 + xm] = (u16)((pu + 0x8000u) >> 16);
          }
          lrow[ti][r] += rs;
        }
    }
    // O += P V   (P: own LDS rows; V fragments: direct global 16B loads)
    #pragma unroll
    for (int kb = 0; kb < 4; kb++) {
      short8 vf[4];
      #pragma unroll
      for (int dj = 0; dj < 4; dj++)
        vf[dj] = *(const short8*)&vgt[(dj * 16 + l15) * 1024 + kb * 32 + quad * 8];
      short8 pf0 = *(const short8*)&pw[l15 * 128 + ((kb * 4 + quad) ^ xm) * 8];
      short8 pf1 = *(const short8*)&pw[(16 + l15) * 128 + ((kb * 4 + quad) ^ xm) * 8];
      #pragma unroll
      for (int dj = 0; dj < 4; dj++) {
        oacc[0][dj] = __builtin_amdgcn_mfma_f32_16x16x32_bf16(pf0, vf[dj], oacc[0][dj], 0, 0, 0);
        oacc[1][dj] = __builtin_amdgcn_mfma_f32_16x16x32_bf16(pf1, vf[dj], oacc[1][dj], 0, 0, 0);
      }
    }
  }
  // epilogue: reduce row sums across 16-lane col groups, normalize, store
  #pragma unroll
  for (int ti = 0; ti < 2; ti++)
    #pragma unroll
    for (int r = 0; r < 4; r++) {
      float s = lrow[ti][r];
      s += __shfl_xor(s, 1); s += __shfl_xor(s, 2);
      s += __shfl_xor(s, 4); s += __shfl_xor(s, 8);
      float inv = 1.f / s;
      int row = w * 32 + ti * 16 + quad * 4 + r;
      size_t ob = ((size_t)(b * 1024 + qt * 128 + row)) * 512 + h * 64;
      #pragma unroll
      for (int dj = 0; dj < 4; dj++)
        attn_out[ob + dj * 16 + l15] = f2bf(oacc[ti][dj][r] * inv);
    }
}

// ---------------- GEMM3: out = attn @ w_out + b_out (fp32 out) ---------------
__global__ __launch_bounds__(256) void k_gemm_out(const u16* __restrict__ ab, const u16* __restrict__ wT,
                                                  const float* __restrict__ bout, float* __restrict__ out) {
  __shared__ u16 sm[8192];
  const int bn = blockIdx.x, bm = blockIdx.y;
  const int tid = threadIdx.x, w = tid >> 6, lane = tid & 63;
  const int quad = lane >> 4, l15 = lane & 15;
  const int wr = w >> 1, wc = w & 1;
  const u16* Ag = ab + (size_t)bm * 128 * 512;
  const u16* Bg = wT + (size_t)bn * 128 * 512;
  float bv[4];
  #pragma unroll
  for (int tj = 0; tj < 4; tj++) bv[tj] = bout[bn * 128 + wc * 64 + tj * 16 + l15];
  floatx4 acc[4][4];
  floatx4 zero = {0.f, 0.f, 0.f, 0.f};
  #pragma unroll
  for (int i = 0; i < 4; i++)
    #pragma unroll
    for (int j = 0; j < 4; j++) acc[i][j] = zero;

  for (int kb = 0; kb < 512; kb += 32) {
    __syncthreads();
    #pragma unroll
    for (int i = 0; i < 2; i++) {
      int c = w * 128 + i * 64 + lane;
      int row = c >> 2, col = (c & 3) * 8;
      gl_lds16(Ag + (size_t)row * 512 + kb + col, &sm[(w * 128 + i * 64) * 8]);
      gl_lds16(Bg + (size_t)row * 512 + kb + col, &sm[4096 + (w * 128 + i * 64) * 8]);
    }
    __syncthreads();
    short8 af[4], bf[4];
    #pragma unroll
    for (int ti = 0; ti < 4; ti++)
      af[ti] = *(const short8*)&sm[(wr * 64 + ti * 16 + l15) * 32 + quad * 8];
    #pragma unroll
    for (int tj = 0; tj < 4; tj++)
      bf[tj] = *(const short8*)&sm[4096 + (wc * 64 + tj * 16 + l15) * 32 + quad * 8];
    #pragma unroll
    for (int ti = 0; ti < 4; ti++)
      #pragma unroll
      for (int tj = 0; tj < 4; tj++)
        acc[ti][tj] = __builtin_amdgcn_mfma_f32_16x16x32_bf16(af[ti], bf[tj], acc[ti][tj], 0, 0, 0);
  }
  #pragma unroll
  for (int ti = 0; ti < 4; ti++)
    #pragma unroll
    for (int tj = 0; tj < 4; tj++)
      #pragma unroll
      for (int r = 0; r < 4; r++) {
        int row = bm * 128 + wr * 64 + ti * 16 + quad * 4 + r;
        int colg = bn * 128 + wc * 64 + tj * 16 + l15;
        out[(size_t)row * 512 + colg] = acc[ti][tj][r] + bv[tj];
      }
}

// ---------------- launch -----------------------------------------------------
extern "C" void kernel_launch(void* const* d_in, const int* in_sizes, int n_in,
                              void* d_out, int out_size, void* d_ws, size_t ws_size,
                              hipStream_t stream) {
  const float* x    = (const float*)d_in[0];
  const float* wqkv = (const float*)d_in[1];
  const float* wout = (const float*)d_in[2];
  const float* bout = (const float*)d_in[3];
  const float* btab = (const float*)d_in[4];
  const int*   rel  = (const int*)d_in[5];
  char* ws = (char*)d_ws;
  u16* xb    = (u16*)(ws + 0);           // x bf16, reused as attn_out
  u16* qbuf  = (u16*)(ws + 33554432);
  u16* kbuf  = (u16*)(ws + 67108864);
  u16* vtbuf = (u16*)(ws + 100663296);
  u16* biasb = (u16*)(ws + 134217728);
  u16* wqkvT = (u16*)(ws + 150994944);
  u16* woutT = (u16*)(ws + 152567808);
  float* out = (float*)d_out;

  k_cast_x  <<<8192, 256, 0, stream>>>(x, xb);
  k_prep_w  <<<4096, 256, 0, stream>>>(wqkv, wout, wqkvT, woutT);
  k_prep_bias<<<4096, 256, 0, stream>>>(rel, btab, biasb);
  k_gemm_qkv<<<dim3(12, 256), 256, 0, stream>>>(xb, wqkvT, qbuf, kbuf, vtbuf);
  k_attn    <<<dim3(32, 64), 256, 0, stream>>>(qbuf, kbuf, vtbuf, biasb, xb);
  k_gemm_out<<<dim3(4, 256), 256, 0, stream>>>(xb, woutT, bout, out);
}

// Round 4
// 388.258 us; speedup vs baseline: 1.8933x; 1.8933x over previous
//
#include <hip/hip_runtime.h>
#include <stdint.h>

typedef unsigned short u16;
typedef __attribute__((ext_vector_type(8))) short short8;   // 8 x bf16 (4 VGPRs)
typedef __attribute__((ext_vector_type(4))) float floatx4;  // MFMA 16x16 C/D

__device__ __forceinline__ u16 f2bf(float f) {
  union { float f; unsigned u; } v; v.f = f;
  return (u16)((v.u + 0x7FFFu + ((v.u >> 16) & 1u)) >> 16);  // RNE
}
__device__ __forceinline__ void gl_lds16(const void* g, void* l) {
  __builtin_amdgcn_global_load_lds((const __attribute__((address_space(1))) void*)g,
                                   (__attribute__((address_space(3))) void*)l, 16, 0, 0);
}
__device__ __forceinline__ float exp2_fast(float x) {
#if __has_builtin(__builtin_amdgcn_exp2f)
  return __builtin_amdgcn_exp2f(x);
#else
  return exp2f(x);
#endif
}

// ---------------- prep: cast x (fp32 -> bf16), 8 elems/thread ----------------
__global__ __launch_bounds__(256) void k_cast_x(const float* __restrict__ x, u16* __restrict__ xb) {
  int t = blockIdx.x * 256 + threadIdx.x;
  const float4* xv = (const float4*)x;
  float4 a = xv[2 * t], b = xv[2 * t + 1];
  short8 o;
  o[0] = f2bf(a.x); o[1] = f2bf(a.y); o[2] = f2bf(a.z); o[3] = f2bf(a.w);
  o[4] = f2bf(b.x); o[5] = f2bf(b.y); o[6] = f2bf(b.z); o[7] = f2bf(b.w);
  ((short8*)xb)[t] = o;
}

// ------------- prep: transpose+cast w_qkv [512,1536] and w_out [512,512] -----
__global__ __launch_bounds__(256) void k_prep_w(const float* __restrict__ wqkv, const float* __restrict__ wout,
                                                u16* __restrict__ wqkvT, u16* __restrict__ woutT) {
  int t = blockIdx.x * 256 + threadIdx.x;
  if (t < 786432) {
    int n = t >> 9, k = t & 511;
    wqkvT[t] = f2bf(wqkv[k * 1536 + n]);
  } else {
    int u = t - 786432;
    int n = u >> 9, k = u & 511;
    woutT[u] = f2bf(wout[k * 512 + n]);
  }
}

// ---- prep: bias pre-swizzled to attn lane order, value = (b-8)*log2e bf16 ---
// memory layout (u16): [h][qt][kt][w][quad][l15][ti][r][tj]; one thread = 8 tj.
__global__ __launch_bounds__(256) void k_prep_bias(const int* __restrict__ rel, const float* __restrict__ tab,
                                                   u16* __restrict__ biasb) {
  int t = blockIdx.x * 256 + threadIdx.x;   // 1,048,576 threads
  int r    = t & 3;
  int ti   = (t >> 2) & 1;
  int l15  = (t >> 3) & 15;
  int quad = (t >> 7) & 3;
  int w    = (t >> 9) & 3;
  int kt   = (t >> 11) & 7;
  int qt   = (t >> 14) & 7;
  int h    = t >> 17;
  int qrow = qt * 128 + w * 32 + ti * 16 + quad * 4 + r;
  const int* rr = rel + qrow * 1024 + kt * 128 + l15;
  short8 o;
  #pragma unroll
  for (int tj = 0; tj < 8; tj++) {
    int idx = rr[tj * 16];
    o[tj] = f2bf((tab[idx * 8 + h] - 8.0f) * 1.44269504f);
  }
  ((short8*)biasb)[t] = o;
}

// ---------------- GEMM1: qkv = xb @ wqkvT^T -> Q,K [b,h,n,d], V^T [b,h,d,n] --
__global__ __launch_bounds__(256) void k_gemm_qkv(const u16* __restrict__ xb, const u16* __restrict__ wT,
                                                  u16* __restrict__ qbuf, u16* __restrict__ kbuf,
                                                  u16* __restrict__ vtbuf) {
  __shared__ u16 sm[17408];
  const int bn = blockIdx.x, bm = blockIdx.y;
  const int tid = threadIdx.x, w = tid >> 6, lane = tid & 63;
  const int quad = lane >> 4, l15 = lane & 15;
  const int wr = w >> 1, wc = w & 1;
  const u16* Ag = xb + (size_t)bm * 128 * 512;
  const u16* Bg = wT + (size_t)bn * 128 * 512;
  floatx4 acc[4][4];
  floatx4 zero = {0.f, 0.f, 0.f, 0.f};
  #pragma unroll
  for (int i = 0; i < 4; i++)
    #pragma unroll
    for (int j = 0; j < 4; j++) acc[i][j] = zero;

  for (int kb = 0; kb < 512; kb += 32) {
    __syncthreads();
    #pragma unroll
    for (int i = 0; i < 2; i++) {
      int c = w * 128 + i * 64 + lane;
      int row = c >> 2, col = (c & 3) * 8;
      gl_lds16(Ag + (size_t)row * 512 + kb + col, &sm[(w * 128 + i * 64) * 8]);
      gl_lds16(Bg + (size_t)row * 512 + kb + col, &sm[4096 + (w * 128 + i * 64) * 8]);
    }
    __syncthreads();
    short8 af[4], bf[4];
    #pragma unroll
    for (int ti = 0; ti < 4; ti++)
      af[ti] = *(const short8*)&sm[(wr * 64 + ti * 16 + l15) * 32 + quad * 8];
    #pragma unroll
    for (int tj = 0; tj < 4; tj++)
      bf[tj] = *(const short8*)&sm[4096 + (wc * 64 + tj * 16 + l15) * 32 + quad * 8];
    #pragma unroll
    for (int ti = 0; ti < 4; ti++)
      #pragma unroll
      for (int tj = 0; tj < 4; tj++)
        acc[ti][tj] = __builtin_amdgcn_mfma_f32_16x16x32_bf16(af[ti], bf[tj], acc[ti][tj], 0, 0, 0);
  }
  __syncthreads();
  #pragma unroll
  for (int ti = 0; ti < 4; ti++)
    #pragma unroll
    for (int tj = 0; tj < 4; tj++)
      #pragma unroll
      for (int r = 0; r < 4; r++)
        sm[(wr * 64 + ti * 16 + quad * 4 + r) * 136 + wc * 64 + tj * 16 + l15] = f2bf(acc[ti][tj][r]);
  __syncthreads();
  const int b = bm >> 3;
  const int nrow0 = (bm & 7) * 128;
  if (bn < 8) {
    u16* dst = (bn < 4) ? qbuf : kbuf;
    #pragma unroll
    for (int i = 0; i < 8; i++) {
      int chunk = i * 256 + tid;
      int r = chunk >> 4, c8 = chunk & 15;
      int nin = (bn & 3) * 128 + c8 * 8;
      int h = nin >> 6, d = nin & 63;
      uint4 val = *(const uint4*)&sm[r * 136 + c8 * 8];
      *(uint4*)&dst[(((size_t)(b * 8 + h)) * 1024 + nrow0 + r) * 64 + d] = val;
    }
  } else {
    #pragma unroll
    for (int i = 0; i < 8; i++) {
      int chunk = i * 256 + tid;
      int dcol = chunk & 127, nr8 = chunk >> 7;
      int nin = (bn & 3) * 128 + dcol;
      int h = nin >> 6, d = nin & 63;
      short8 v;
      #pragma unroll
      for (int j = 0; j < 8; j++) v[j] = (short)sm[(nr8 * 8 + j) * 136 + dcol];
      *(short8*)&vtbuf[(((size_t)(b * 8 + h)) * 64 + d) * 1024 + nrow0 + nr8 * 8] = v;
    }
  }
}

// ---------------- flash attention v4: double-buffered K/V, 1 barrier/kt ------
// LDS (u16 idx): K0 [0,8192) V0 [8192,16384) K1 [16384,24576) V1 [24576,32768)
//                P [32768,40960)  -- 80 KB total -> 2 blocks/CU.
// Prefetch for kt+1 issued at top of iter kt; the single end-of-iter barrier's
// vmcnt(0) waits a DMA that aged through the whole compute phase (no drain
// stall).  kt is processed in two kv-halves (64 cols each) so P is only 16 KB;
// P is wave-private (write+read same wave, in-order DS pipe, no barrier).
__global__ __launch_bounds__(256, 2) void k_attn(const u16* __restrict__ qbuf, const u16* __restrict__ kbuf,
                                                 const u16* __restrict__ vtbuf, const u16* __restrict__ biasb,
                                                 u16* __restrict__ attn_out) {
  __shared__ u16 sm[40960];
  const int PO = 32768;
  const int b = blockIdx.x, h = blockIdx.y >> 3, qt = blockIdx.y & 7;
  const int tid = threadIdx.x, w = tid >> 6, lane = tid & 63;
  const int quad = lane >> 4, l15 = lane & 15;
  const int xm = l15 & 7;
  u16* pw = &sm[PO + w * 2048];                 // wave-private P: 32 rows x 64
  const size_t bh = (size_t)(b * 8 + h);
  const u16* qg = qbuf + (bh * 1024 + (size_t)qt * 128) * 64;
  const u16* kg = kbuf + bh * 1024 * 64;
  const u16* vg = vtbuf + bh * 64 * 1024;
  const u16* bg = biasb + (size_t)h * 1048576 + (size_t)qt * 131072 +
                  (size_t)w * 4096 + quad * 1024 + l15 * 64;

  // staging source indices (swizzled), loop-invariant
  int rK[4], cK[4], dV[4], cV[4];
  #pragma unroll
  for (int i = 0; i < 4; i++) {
    int p = (w * 4 + i) * 64 + lane;
    rK[i] = p >> 3;  cK[i] = (p & 7) ^ (rK[i] & 7);
    dV[i] = p >> 4;  cV[i] = (p & 15) ^ (dV[i] & 7);
  }

  // Q fragments: direct global 16B loads (once per block)
  short8 qf[2][2];
  #pragma unroll
  for (int ti = 0; ti < 2; ti++)
    #pragma unroll
    for (int kk = 0; kk < 2; kk++)
      qf[ti][kk] = *(const short8*)&qg[(w * 32 + ti * 16 + l15) * 64 + kk * 32 + quad * 8];

  floatx4 oacc[2][4];
  floatx4 zero = {0.f, 0.f, 0.f, 0.f};
  #pragma unroll
  for (int i = 0; i < 2; i++)
    #pragma unroll
    for (int j = 0; j < 4; j++) oacc[i][j] = zero;
  float lrow[2][4];
  #pragma unroll
  for (int i = 0; i < 2; i++)
    #pragma unroll
    for (int r = 0; r < 4; r++) lrow[i][r] = 0.f;

  const float SC = 0.125f * 1.44269504f;

  // preload tile 0 into buffer 0
  #pragma unroll
  for (int i = 0; i < 4; i++) {
    gl_lds16(kg + (size_t)rK[i] * 64 + cK[i] * 8, &sm[(w * 4 + i) * 512]);
    gl_lds16(vg + (size_t)dV[i] * 1024 + cV[i] * 8, &sm[8192 + (w * 4 + i) * 512]);
  }
  __syncthreads();   // vmcnt(0) drain + sync: tile 0 resident

  for (int kt = 0; kt < 8; kt++) {
    const int cur = (kt & 1) ? 16384 : 0;
    const int nxt = (kt & 1) ? 0 : 16384;
    // prefetch kt+1 (buffer nxt was last read in kt-1; synced by prev barrier)
    if (kt < 7) {
      #pragma unroll
      for (int i = 0; i < 4; i++) {
        gl_lds16(kg + (size_t)((kt + 1) * 128 + rK[i]) * 64 + cK[i] * 8, &sm[nxt + (w * 4 + i) * 512]);
        gl_lds16(vg + (size_t)dV[i] * 1024 + (kt + 1) * 128 + cV[i] * 8, &sm[nxt + 8192 + (w * 4 + i) * 512]);
      }
    }
    // bias for the whole kt (issued early; latency hides under QK)
    const u16* bkt = bg + kt * 16384;
    uint2 bu[2][4][2];
    #pragma unroll
    for (int ti = 0; ti < 2; ti++)
      #pragma unroll
      for (int r = 0; r < 4; r++) {
        bu[ti][r][0] = *(const uint2*)&bkt[(ti * 4 + r) * 8];
        bu[ti][r][1] = *(const uint2*)&bkt[(ti * 4 + r) * 8 + 4];
      }

    #pragma unroll
    for (int tjh = 0; tjh < 2; tjh++) {
      // S = Q K^T for this 64-col half
      floatx4 sacc[2][4];
      #pragma unroll
      for (int tjl = 0; tjl < 4; tjl++) { sacc[0][tjl] = zero; sacc[1][tjl] = zero; }
      #pragma unroll
      for (int tjl = 0; tjl < 4; tjl++) {
        int tj = tjh * 4 + tjl;
        #pragma unroll
        for (int kk = 0; kk < 2; kk++) {
          short8 kf = *(const short8*)&sm[cur + (tj * 16 + l15) * 64 + ((kk * 4 + quad) ^ xm) * 8];
          sacc[0][tjl] = __builtin_amdgcn_mfma_f32_16x16x32_bf16(qf[0][kk], kf, sacc[0][tjl], 0, 0, 0);
          sacc[1][tjl] = __builtin_amdgcn_mfma_f32_16x16x32_bf16(qf[1][kk], kf, sacc[1][tjl], 0, 0, 0);
        }
      }
      // softmax (no max-subtract) + P -> wave-private LDS half (swizzled)
      #pragma unroll
      for (int ti = 0; ti < 2; ti++)
        #pragma unroll
        for (int r = 0; r < 4; r++) {
          int lr = ti * 16 + quad * 4 + r;      // row within wave's 32
          int wm = lr & 7;
          unsigned blo = bu[ti][r][tjh].x, bhi = bu[ti][r][tjh].y;
          float bf32[4];
          bf32[0] = __builtin_bit_cast(float, blo << 16);
          bf32[1] = __builtin_bit_cast(float, blo & 0xFFFF0000u);
          bf32[2] = __builtin_bit_cast(float, bhi << 16);
          bf32[3] = __builtin_bit_cast(float, bhi & 0xFFFF0000u);
          float rs = 0.f;
          #pragma unroll
          for (int tjl = 0; tjl < 4; tjl++) {
            float p = exp2_fast(sacc[ti][tjl][r] * SC + bf32[tjl]);
            rs += p;
            unsigned pu = __builtin_bit_cast(unsigned, p);
            int cc = (tjl * 2 + (l15 >> 3)) ^ wm;   // chunk within 64-col half
            pw[lr * 64 + cc * 8 + xm] = (u16)((pu + 0x8000u) >> 16);
          }
          lrow[ti][r] += rs;
        }
      // O += P_half V_half   (V rows tjh*64 .. +63)
      #pragma unroll
      for (int kbl = 0; kbl < 2; kbl++) {
        short8 pf0 = *(const short8*)&pw[l15 * 64 + ((kbl * 4 + quad) ^ xm) * 8];
        short8 pf1 = *(const short8*)&pw[(16 + l15) * 64 + ((kbl * 4 + quad) ^ xm) * 8];
        #pragma unroll
        for (int dj = 0; dj < 4; dj++) {
          int kc = (tjh * 8 + kbl * 4 + quad) ^ xm;   // V chunk (16 per row)
          short8 vf = *(const short8*)&sm[cur + 8192 + (dj * 16 + l15) * 128 + kc * 8];
          oacc[0][dj] = __builtin_amdgcn_mfma_f32_16x16x32_bf16(pf0, vf, oacc[0][dj], 0, 0, 0);
          oacc[1][dj] = __builtin_amdgcn_mfma_f32_16x16x32_bf16(pf1, vf, oacc[1][dj], 0, 0, 0);
        }
      }
    }
    __syncthreads();  // single barrier: syncs buffer handoff; vmcnt(0) drains a
                      // prefetch that aged through the whole compute phase
  }

  // epilogue: reduce row sums across 16-lane col groups, normalize, store
  #pragma unroll
  for (int ti = 0; ti < 2; ti++)
    #pragma unroll
    for (int r = 0; r < 4; r++) {
      float s = lrow[ti][r];
      s += __shfl_xor(s, 1); s += __shfl_xor(s, 2);
      s += __shfl_xor(s, 4); s += __shfl_xor(s, 8);
      float inv = 1.f / s;
      int row = w * 32 + ti * 16 + quad * 4 + r;
      size_t ob = ((size_t)(b * 1024 + qt * 128 + row)) * 512 + h * 64;
      #pragma unroll
      for (int dj = 0; dj < 4; dj++)
        attn_out[ob + dj * 16 + l15] = f2bf(oacc[ti][dj][r] * inv);
    }
}

// ---------------- GEMM3: out = attn @ w_out + b_out (fp32 out) ---------------
__global__ __launch_bounds__(256) void k_gemm_out(const u16* __restrict__ ab, const u16* __restrict__ wT,
                                                  const float* __restrict__ bout, float* __restrict__ out) {
  __shared__ u16 sm[8192];
  const int bn = blockIdx.x, bm = blockIdx.y;
  const int tid = threadIdx.x, w = tid >> 6, lane = tid & 63;
  const int quad = lane >> 4, l15 = lane & 15;
  const int wr = w >> 1, wc = w & 1;
  const u16* Ag = ab + (size_t)bm * 128 * 512;
  const u16* Bg = wT + (size_t)bn * 128 * 512;
  float bv[4];
  #pragma unroll
  for (int tj = 0; tj < 4; tj++) bv[tj] = bout[bn * 128 + wc * 64 + tj * 16 + l15];
  floatx4 acc[4][4];
  floatx4 zero = {0.f, 0.f, 0.f, 0.f};
  #pragma unroll
  for (int i = 0; i < 4; i++)
    #pragma unroll
    for (int j = 0; j < 4; j++) acc[i][j] = zero;

  for (int kb = 0; kb < 512; kb += 32) {
    __syncthreads();
    #pragma unroll
    for (int i = 0; i < 2; i++) {
      int c = w * 128 + i * 64 + lane;
      int row = c >> 2, col = (c & 3) * 8;
      gl_lds16(Ag + (size_t)row * 512 + kb + col, &sm[(w * 128 + i * 64) * 8]);
      gl_lds16(Bg + (size_t)row * 512 + kb + col, &sm[4096 + (w * 128 + i * 64) * 8]);
    }
    __syncthreads();
    short8 af[4], bf[4];
    #pragma unroll
    for (int ti = 0; ti < 4; ti++)
      af[ti] = *(const short8*)&sm[(wr * 64 + ti * 16 + l15) * 32 + quad * 8];
    #pragma unroll
    for (int tj = 0; tj < 4; tj++)
      bf[tj] = *(const short8*)&sm[4096 + (wc * 64 + tj * 16 + l15) * 32 + quad * 8];
    #pragma unroll
    for (int ti = 0; ti < 4; ti++)
      #pragma unroll
      for (int tj = 0; tj < 4; tj++)
        acc[ti][tj] = __builtin_amdgcn_mfma_f32_16x16x32_bf16(af[ti], bf[tj], acc[ti][tj], 0, 0, 0);
  }
  #pragma unroll
  for (int ti = 0; ti < 4; ti++)
    #pragma unroll
    for (int tj = 0; tj < 4; tj++)
      #pragma unroll
      for (int r = 0; r < 4; r++) {
        int row = bm * 128 + wr * 64 + ti * 16 + quad * 4 + r;
        int colg = bn * 128 + wc * 64 + tj * 16 + l15;
        out[(size_t)row * 512 + colg] = acc[ti][tj][r] + bv[tj];
      }
}

// ---------------- launch -----------------------------------------------------
extern "C" void kernel_launch(void* const* d_in, const int* in_sizes, int n_in,
                              void* d_out, int out_size, void* d_ws, size_t ws_size,
                              hipStream_t stream) {
  const float* x    = (const float*)d_in[0];
  const float* wqkv = (const float*)d_in[1];
  const float* wout = (const float*)d_in[2];
  const float* bout = (const float*)d_in[3];
  const float* btab = (const float*)d_in[4];
  const int*   rel  = (const int*)d_in[5];
  char* ws = (char*)d_ws;
  u16* xb    = (u16*)(ws + 0);           // x bf16, reused as attn_out
  u16* qbuf  = (u16*)(ws + 33554432);
  u16* kbuf  = (u16*)(ws + 67108864);
  u16* vtbuf = (u16*)(ws + 100663296);
  u16* biasb = (u16*)(ws + 134217728);
  u16* wqkvT = (u16*)(ws + 150994944);
  u16* woutT = (u16*)(ws + 152567808);
  float* out = (float*)d_out;

  k_cast_x  <<<8192, 256, 0, stream>>>(x, xb);
  k_prep_w  <<<4096, 256, 0, stream>>>(wqkv, wout, wqkvT, woutT);
  k_prep_bias<<<4096, 256, 0, stream>>>(rel, btab, biasb);
  k_gemm_qkv<<<dim3(12, 256), 256, 0, stream>>>(xb, wqkvT, qbuf, kbuf, vtbuf);
  k_attn    <<<dim3(32, 64), 256, 0, stream>>>(qbuf, kbuf, vtbuf, biasb, xb);
  k_gemm_out<<<dim3(4, 256), 256, 0, stream>>>(xb, woutT, bout, out);
}